// Round 1
// baseline (151.846 us; speedup 1.0000x reference)
//
#include <hip/hip_runtime.h>
#include <hip/hip_bf16.h>
#include <stdint.h>

#define C_IN  256
#define C_OUT 256
#define H_IN  224
#define W_IN  224
#define HP    226
#define WP    226
#define NPIX  (H_IN * W_IN)   // 50176 = 392 * 128
#define BM    128
#define BN    128
#define BK    32
#define RS    40              // LDS row stride (elements): 32 + 8 pad

typedef __attribute__((ext_vector_type(8))) short short8;
typedef __attribute__((ext_vector_type(4))) float f32x4;

__device__ __forceinline__ unsigned short f2bf(float f) {
    union { float f; uint32_t u; } v; v.f = f;
    uint32_t u = v.u;
    u += 0x7FFFu + ((u >> 16) & 1u);   // round-to-nearest-even
    return (unsigned short)(u >> 16);
}

// ---------- prep kernels ----------

__global__ void zero_u4(uint4* p, int n) {
    int i = blockIdx.x * blockDim.x + threadIdx.x;
    int st = gridDim.x * blockDim.x;
    uint4 z = make_uint4(0u, 0u, 0u, 0u);
    for (; i < n; i += st) p[i] = z;
}

// x [C][H][W] f32 -> xp [HP][WP][C] bf16 (interior; borders pre-zeroed)
__global__ void prep_x(const float* __restrict__ x, unsigned short* __restrict__ xp) {
    int b  = blockIdx.x;
    int ct = b & 3, wt = (b >> 2) & 3, h = b >> 4;   // grid = 224*4*4
    int c0 = ct * 64, w0 = wt * 64;
    int t  = threadIdx.x;
    __shared__ float tile[64][65];

    int w   = t & 63;
    int cl0 = t >> 6;      // 0..3
    #pragma unroll
    for (int i = 0; i < 16; ++i) {
        int cl = i * 4 + cl0;
        float v = 0.f;
        if (w0 + w < W_IN)
            v = x[(size_t)(c0 + cl) * NPIX + (size_t)h * W_IN + w0 + w];
        tile[cl][w] = v;
    }
    __syncthreads();

    int wc = t >> 2;           // 0..63
    int cc = (t & 3) * 16;     // 0,16,32,48
    if (w0 + wc < W_IN) {
        uint32_t pk[8];
        #pragma unroll
        for (int j = 0; j < 8; ++j) {
            unsigned short lo = f2bf(tile[cc + 2 * j][wc]);
            unsigned short hi = f2bf(tile[cc + 2 * j + 1][wc]);
            pk[j] = (uint32_t)lo | ((uint32_t)hi << 16);
        }
        size_t base = ((size_t)(h + 1) * WP + (w0 + wc + 1)) * C_IN + c0 + cc;
        uint4* dst = (uint4*)(xp + base);
        dst[0] = make_uint4(pk[0], pk[1], pk[2], pk[3]);
        dst[1] = make_uint4(pk[4], pk[5], pk[6], pk[7]);
    }
}

// W [O][C][3][3] f32 -> wb [p][O][C] bf16
__global__ void prep_w(const float* __restrict__ wk, unsigned short* __restrict__ wb) {
    int idx = blockIdx.x * 256 + threadIdx.x;         // 9*256*256 total
    int c = idx & 255, o = (idx >> 8) & 255, p = idx >> 16;
    wb[((size_t)p * 256 + o) * 256 + c] = f2bf(wk[((size_t)o * 256 + c) * 9 + p]);
}

// ---------- main GEMM: out[o][n] = sum_p sum_c wb[p][o][c] * xp[colbase(n,p)][c] ----------

__launch_bounds__(256, 2)
__global__ void conv_gemm(const unsigned short* __restrict__ xp,
                          const unsigned short* __restrict__ wb,
                          float* __restrict__ out) {
    int bid = blockIdx.x;      // 784 = 392 n-tiles * 2 m-tiles; m-tiles adjacent for B-tile L2 reuse
    int mt = bid & 1;
    int nt = bid >> 1;
    int m0 = mt * BM;
    int n0 = nt * BN;
    int t  = threadIdx.x;
    int l  = t & 63, wv = t >> 6;

    __shared__ unsigned short lA[BM * RS];
    __shared__ unsigned short lB[BN * RS];

    // staging mapping: 2 threads per row, 16 c each (32B)
    int srow  = t >> 1;           // 0..127
    int shalf = (t & 1) * 16;     // 0 or 16 (elements)

    int n_col = n0 + srow;
    int h = n_col / W_IN;
    int w = n_col - h * W_IN;

    // wave sub-tile (2x2 waves, 64x64 each)
    int mo = (wv >> 1) * 64;
    int no = (wv & 1) * 64;

    f32x4 acc[4][4];
    #pragma unroll
    for (int i = 0; i < 4; ++i)
        #pragma unroll
        for (int j = 0; j < 4; ++j)
            acc[i][j] = f32x4{0.f, 0.f, 0.f, 0.f};

    int la = l & 15;
    int lk = (l >> 4) * 8;

    for (int p = 0; p < 9; ++p) {
        int kh = p / 3, kw = p - kh * 3;
        size_t bbase = ((size_t)(h + kh) * WP + (w + kw)) * C_IN;   // xp row for this tap
        size_t abase = ((size_t)p * 256 + m0 + srow) * C_IN;
        for (int cs = 0; cs < C_IN; cs += BK) {
            __syncthreads();   // previous compute done before overwrite
            const uint4* ga = (const uint4*)(wb + abase + cs + shalf);
            uint4 va0 = ga[0], va1 = ga[1];
            const uint4* gb = (const uint4*)(xp + bbase + cs + shalf);
            uint4 vb0 = gb[0], vb1 = gb[1];
            *(uint4*)&lA[srow * RS + shalf]     = va0;
            *(uint4*)&lA[srow * RS + shalf + 8] = va1;
            *(uint4*)&lB[srow * RS + shalf]     = vb0;
            *(uint4*)&lB[srow * RS + shalf + 8] = vb1;
            __syncthreads();

            short8 af[4], bf[4];
            #pragma unroll
            for (int i = 0; i < 4; ++i)
                af[i] = *(const short8*)&lA[(mo + i * 16 + la) * RS + lk];
            #pragma unroll
            for (int i = 0; i < 4; ++i)
                bf[i] = *(const short8*)&lB[(no + i * 16 + la) * RS + lk];

            #pragma unroll
            for (int i = 0; i < 4; ++i)
                #pragma unroll
                for (int j = 0; j < 4; ++j)
                    acc[i][j] = __builtin_amdgcn_mfma_f32_16x16x32_bf16(
                        af[i], bf[j], acc[i][j], 0, 0, 0);
        }
    }

    // epilogue: D frag col = l&15 (n), row = (l>>4)*4 + r (o)
    int ro = (l >> 4) * 4;
    #pragma unroll
    for (int i = 0; i < 4; ++i) {
        #pragma unroll
        for (int j = 0; j < 4; ++j) {
            int oo = m0 + mo + i * 16 + ro;
            int nn = n0 + no + j * 16 + la;
            #pragma unroll
            for (int r = 0; r < 4; ++r)
                out[(size_t)(oo + r) * NPIX + nn] = acc[i][j][r];
        }
    }
}

// ---------- fallback (tiny ws): naive direct conv, correct but slow ----------
__global__ void conv_naive(const float* __restrict__ x, const float* __restrict__ wk,
                           float* __restrict__ out) {
    int idx = blockIdx.x * 256 + threadIdx.x;   // o*NPIX + n
    int n = idx % NPIX;
    int o = idx / NPIX;
    int h = n / W_IN, w = n - (n / W_IN) * W_IN;
    float s = 0.f;
    for (int c = 0; c < C_IN; ++c) {
        const float* xc = x + (size_t)c * NPIX;
        const float* wc = wk + ((size_t)o * C_IN + c) * 9;
        #pragma unroll
        for (int kh = 0; kh < 3; ++kh) {
            int hh = h + kh - 1;
            if (hh < 0 || hh >= H_IN) continue;
            #pragma unroll
            for (int kw = 0; kw < 3; ++kw) {
                int ww = w + kw - 1;
                if (ww < 0 || ww >= W_IN) continue;
                s += xc[hh * W_IN + ww] * wc[kh * 3 + kw];
            }
        }
    }
    out[idx] = s;
}

extern "C" void kernel_launch(void* const* d_in, const int* in_sizes, int n_in,
                              void* d_out, int out_size, void* d_ws, size_t ws_size,
                              hipStream_t stream) {
    const float* x  = (const float*)d_in[0];
    const float* wk = (const float*)d_in[1];
    float* out = (float*)d_out;

    const size_t xp_elems = (size_t)HP * WP * C_IN;   // 13,075,456
    const size_t wb_elems = (size_t)9 * 256 * 256;    // 589,824
    const size_t need = (xp_elems + wb_elems) * 2;    // ~27.3 MB

    if (ws_size < need) {
        conv_naive<<<(C_OUT * NPIX) / 256, 256, 0, stream>>>(x, wk, out);
        return;
    }

    unsigned short* xp = (unsigned short*)d_ws;
    unsigned short* wb = xp + xp_elems;

    zero_u4<<<1024, 256, 0, stream>>>((uint4*)d_ws, (int)(xp_elems * 2 / 16));
    prep_x<<<224 * 16, 256, 0, stream>>>(x, xp);
    prep_w<<<2304, 256, 0, stream>>>(wk, wb);
    conv_gemm<<<392 * 2, 256, 0, stream>>>(xp, wb, out);
}

// Round 2
// 115.944 us; speedup vs baseline: 1.3097x; 1.3097x over previous
//
#include <hip/hip_runtime.h>
#include <hip/hip_bf16.h>
#include <stdint.h>

#define C_IN  256
#define C_OUT 256
#define H_IN  224
#define W_IN  224
#define HP    226
#define WP    226
#define NPIX  (H_IN * W_IN)   // 50176 = 392 * 128
#define BM    128
#define BN    128
#define BK    64              // 64 elems = 128 B rows -> XOR swizzle is conflict-free

typedef __attribute__((ext_vector_type(8))) short short8;
typedef __attribute__((ext_vector_type(4))) float f32x4;

__device__ __forceinline__ unsigned short f2bf(float f) {
    union { float f; uint32_t u; } v; v.f = f;
    uint32_t u = v.u;
    u += 0x7FFFu + ((u >> 16) & 1u);   // round-to-nearest-even
    return (unsigned short)(u >> 16);
}

// async global->LDS, 16B per lane; LDS dest is wave-uniform base + lane*16
__device__ __forceinline__ void gl_lds16(const unsigned short* g, unsigned short* l) {
    __builtin_amdgcn_global_load_lds(
        (const __attribute__((address_space(1))) unsigned int*)g,
        (__attribute__((address_space(3))) unsigned int*)l,
        16, 0, 0);
}

// ---------- prep kernels ----------

__global__ void zero_u4(uint4* p, int n) {
    int i = blockIdx.x * blockDim.x + threadIdx.x;
    int st = gridDim.x * blockDim.x;
    uint4 z = make_uint4(0u, 0u, 0u, 0u);
    for (; i < n; i += st) p[i] = z;
}

// x [C][H][W] f32 -> xp [HP][WP][C] bf16 (interior; borders pre-zeroed)
__global__ void prep_x(const float* __restrict__ x, unsigned short* __restrict__ xp) {
    int b  = blockIdx.x;
    int ct = b & 3, wt = (b >> 2) & 3, h = b >> 4;   // grid = 224*4*4
    int c0 = ct * 64, w0 = wt * 64;
    int t  = threadIdx.x;
    __shared__ float tile[64][65];

    int w   = t & 63;
    int cl0 = t >> 6;      // 0..3
    #pragma unroll
    for (int i = 0; i < 16; ++i) {
        int cl = i * 4 + cl0;
        float v = 0.f;
        if (w0 + w < W_IN)
            v = x[(size_t)(c0 + cl) * NPIX + (size_t)h * W_IN + w0 + w];
        tile[cl][w] = v;
    }
    __syncthreads();

    int wc = t >> 2;           // 0..63
    int cc = (t & 3) * 16;     // 0,16,32,48
    if (w0 + wc < W_IN) {
        uint32_t pk[8];
        #pragma unroll
        for (int j = 0; j < 8; ++j) {
            unsigned short lo = f2bf(tile[cc + 2 * j][wc]);
            unsigned short hi = f2bf(tile[cc + 2 * j + 1][wc]);
            pk[j] = (uint32_t)lo | ((uint32_t)hi << 16);
        }
        size_t base = ((size_t)(h + 1) * WP + (w0 + wc + 1)) * C_IN + c0 + cc;
        uint4* dst = (uint4*)(xp + base);
        dst[0] = make_uint4(pk[0], pk[1], pk[2], pk[3]);
        dst[1] = make_uint4(pk[4], pk[5], pk[6], pk[7]);
    }
}

// W [O][C][3][3] f32 -> wb [p][O][C] bf16
__global__ void prep_w(const float* __restrict__ wk, unsigned short* __restrict__ wb) {
    int idx = blockIdx.x * 256 + threadIdx.x;         // 9*256*256 total
    int c = idx & 255, o = (idx >> 8) & 255, p = idx >> 16;
    wb[((size_t)p * 256 + o) * 256 + c] = f2bf(wk[((size_t)o * 256 + c) * 9 + p]);
}

// ---------- main GEMM: out[o][n] = sum_p sum_c wb[p][o][c] * xp[...][c] ----------
// m97-structure: global_load_lds width=16 into linear LDS [128][64] (128B rows),
// st_16x32-style swizzle: phys_quad = logical_quad ^ (row&7), applied via
// pre-swizzled global source (write side) + XOR'd ds_read address (read side).

__launch_bounds__(256, 2)
__global__ void conv_gemm(const unsigned short* __restrict__ xp,
                          const unsigned short* __restrict__ wb,
                          float* __restrict__ out) {
    // bijective XCD swizzle: 784 % 8 == 0, chunk = 98 per XCD.
    int wgid = (blockIdx.x & 7) * 98 + (blockIdx.x >> 3);
    int mt = wgid & 1;
    int nt = wgid >> 1;
    int m0 = mt * BM;
    int n0 = nt * BN;
    int t  = threadIdx.x;
    int l  = t & 63, wv = t >> 6;

    __shared__ __align__(16) unsigned short lA[BM * BK];   // 16 KB
    __shared__ __align__(16) unsigned short lB[BN * BK];   // 16 KB

    // ---- staging mapping (per global_load_lds instr: wave covers 1 KB = 8 rows) ----
    // instr i = wv*4 + j ; lane l -> row r = i*8 + (l>>3), phys quad qd = l&7,
    // source logical quad q = qd ^ (r&7)  (involution -> read-side XOR matches)
    int r_[4];
    size_t aBase[4];
    size_t bBase[4];
    #pragma unroll
    for (int j = 0; j < 4; ++j) {
        int r = (wv * 4 + j) * 8 + (l >> 3);
        int q = (l & 7) ^ (r & 7);
        r_[j] = r;
        aBase[j] = (size_t)(m0 + r) * C_IN + q * 8;
        unsigned int n_col = n0 + r;
        unsigned int h = n_col / W_IN;
        unsigned int w = n_col - h * W_IN;
        bBase[j] = ((size_t)h * WP + w) * C_IN + q * 8;
    }

    // ---- read-side fragment addressing ----
    int la   = l & 15;
    int lk16 = l >> 4;                 // 0..3 -> k sub-quad
    int mo = (wv >> 1) * 64;
    int no = (wv & 1) * 64;
    // swizzled quad offset (elems) for k-slice ks: ((ks*4 + lk16) ^ (row&7)) * 8 ; row&7 == la&7
    int xq[2];
    #pragma unroll
    for (int ks = 0; ks < 2; ++ks)
        xq[ks] = (((ks * 4 + lk16) ^ (la & 7)) * 8);

    f32x4 acc[4][4];
    #pragma unroll
    for (int i = 0; i < 4; ++i)
        #pragma unroll
        for (int j = 0; j < 4; ++j)
            acc[i][j] = f32x4{0.f, 0.f, 0.f, 0.f};

    #pragma unroll 1
    for (int p = 0; p < 9; ++p) {
        int kh = p / 3, kw = p - kh * 3;
        const unsigned short* wbp = wb + (size_t)p * (256 * 256);
        const unsigned short* xpp = xp + ((size_t)kh * WP + kw) * C_IN;
        #pragma unroll
        for (int cs = 0; cs < C_IN; cs += BK) {
            __syncthreads();   // previous compute done before DMA overwrite
            #pragma unroll
            for (int j = 0; j < 4; ++j) {
                gl_lds16(wbp + aBase[j] + cs, &lA[(wv * 4 + j) * 512]);
                gl_lds16(xpp + bBase[j] + cs, &lB[(wv * 4 + j) * 512]);
            }
            __syncthreads();   // compiler drains vmcnt(0) here -> LDS ready

            short8 af[4][2], bf[4][2];
            #pragma unroll
            for (int i = 0; i < 4; ++i)
                #pragma unroll
                for (int ks = 0; ks < 2; ++ks)
                    af[i][ks] = *(const short8*)&lA[(mo + i * 16 + la) * BK + xq[ks]];
            #pragma unroll
            for (int i = 0; i < 4; ++i)
                #pragma unroll
                for (int ks = 0; ks < 2; ++ks)
                    bf[i][ks] = *(const short8*)&lB[(no + i * 16 + la) * BK + xq[ks]];

            #pragma unroll
            for (int ks = 0; ks < 2; ++ks)
                #pragma unroll
                for (int i = 0; i < 4; ++i)
                    #pragma unroll
                    for (int j = 0; j < 4; ++j)
                        acc[i][j] = __builtin_amdgcn_mfma_f32_16x16x32_bf16(
                            af[i][ks], bf[j][ks], acc[i][j], 0, 0, 0);
        }
    }

    // epilogue: D frag col = l&15 (n), row = (l>>4)*4 + r (o)
    int ro = lk16 * 4;
    #pragma unroll
    for (int i = 0; i < 4; ++i) {
        #pragma unroll
        for (int j = 0; j < 4; ++j) {
            int oo = m0 + mo + i * 16 + ro;
            int nn = n0 + no + j * 16 + la;
            #pragma unroll
            for (int r = 0; r < 4; ++r)
                out[(size_t)(oo + r) * NPIX + nn] = acc[i][j][r];
        }
    }
}

// ---------- fallback (tiny ws): naive direct conv, correct but slow ----------
__global__ void conv_naive(const float* __restrict__ x, const float* __restrict__ wk,
                           float* __restrict__ out) {
    int idx = blockIdx.x * 256 + threadIdx.x;   // o*NPIX + n
    int n = idx % NPIX;
    int o = idx / NPIX;
    int h = n / W_IN, w = n - (n / W_IN) * W_IN;
    float s = 0.f;
    for (int c = 0; c < C_IN; ++c) {
        const float* xc = x + (size_t)c * NPIX;
        const float* wc = wk + ((size_t)o * C_IN + c) * 9;
        #pragma unroll
        for (int kh = 0; kh < 3; ++kh) {
            int hh = h + kh - 1;
            if (hh < 0 || hh >= H_IN) continue;
            #pragma unroll
            for (int kw = 0; kw < 3; ++kw) {
                int ww = w + kw - 1;
                if (ww < 0 || ww >= W_IN) continue;
                s += xc[hh * W_IN + ww] * wc[kh * 3 + kw];
            }
        }
    }
    out[idx] = s;
}

extern "C" void kernel_launch(void* const* d_in, const int* in_sizes, int n_in,
                              void* d_out, int out_size, void* d_ws, size_t ws_size,
                              hipStream_t stream) {
    const float* x  = (const float*)d_in[0];
    const float* wk = (const float*)d_in[1];
    float* out = (float*)d_out;

    const size_t xp_elems = (size_t)HP * WP * C_IN;   // 13,075,456
    const size_t wb_elems = (size_t)9 * 256 * 256;    // 589,824
    const size_t need = (xp_elems + wb_elems) * 2;    // ~27.3 MB

    if (ws_size < need) {
        conv_naive<<<(C_OUT * NPIX) / 256, 256, 0, stream>>>(x, wk, out);
        return;
    }

    unsigned short* xp = (unsigned short*)d_ws;
    unsigned short* wb = xp + xp_elems;

    zero_u4<<<1024, 256, 0, stream>>>((uint4*)d_ws, (int)(xp_elems * 2 / 16));
    prep_x<<<224 * 16, 256, 0, stream>>>(x, xp);
    prep_w<<<2304, 256, 0, stream>>>(wk, wb);
    conv_gemm<<<392 * 2, 256, 0, stream>>>(xp, wb, out);
}

// Round 4
// 108.505 us; speedup vs baseline: 1.3994x; 1.0686x over previous
//
#include <hip/hip_runtime.h>
#include <hip/hip_bf16.h>
#include <stdint.h>

#define C_IN  256
#define C_OUT 256
#define H_IN  224
#define W_IN  224
#define HP    226
#define WP    226
#define NPIX  (H_IN * W_IN)   // 50176 = 392 * 128
#define BM    128
#define BN    128
#define BK    32              // 32 elems = 64 B rows

typedef __attribute__((ext_vector_type(8))) short short8;
typedef __attribute__((ext_vector_type(4))) float f32x4;

__device__ __forceinline__ unsigned short f2bf(float f) {
    __hip_bfloat16 b = __float2bfloat16(f);
    return *(unsigned short*)&b;
}

// async global->LDS, 16B per lane; LDS dest is wave-uniform base + lane*16
__device__ __forceinline__ void gl_lds16(const unsigned short* g, unsigned short* l) {
    __builtin_amdgcn_global_load_lds(
        (const __attribute__((address_space(1))) unsigned int*)g,
        (__attribute__((address_space(3))) unsigned int*)l,
        16, 0, 0);
}

// ---------- prep kernels ----------

// zero only the pad border of xp [HP][WP][C] (interior written by prep_x)
__global__ void zero_border(unsigned short* __restrict__ xp) {
    int i = blockIdx.x * 256 + threadIdx.x;   // uint4 index
    uint4 z = make_uint4(0u, 0u, 0u, 0u);
    if (i < 7232) {                                    // h = 0 row
        ((uint4*)xp)[i] = z;
    } else if (i < 14464) {                            // h = 225 row
        ((uint4*)(xp + (size_t)225 * WP * C_IN))[i - 7232] = z;
    } else if (i < 21632) {                            // w = 0 col, h 1..224
        int j = i - 14464; int h = 1 + (j >> 5); int c4 = j & 31;
        ((uint4*)(xp + ((size_t)h * WP) * C_IN))[c4] = z;
    } else if (i < 28800) {                            // w = 225 col, h 1..224
        int j = i - 21632; int h = 1 + (j >> 5); int c4 = j & 31;
        ((uint4*)(xp + ((size_t)h * WP + 225) * C_IN))[c4] = z;
    }
}

// x [C][H][W] f32 -> xp [HP][WP][C] bf16 (interior only)
__global__ void prep_x(const float* __restrict__ x, unsigned short* __restrict__ xp) {
    int b  = blockIdx.x;
    int ct = b & 3, wt = (b >> 2) & 3, h = b >> 4;   // grid = 224*4*4
    int c0 = ct * 64, w0 = wt * 64;
    int t  = threadIdx.x;
    __shared__ float tile[64][65];

    int w   = t & 63;
    int cl0 = t >> 6;      // 0..3
    #pragma unroll
    for (int i = 0; i < 16; ++i) {
        int cl = i * 4 + cl0;
        float v = 0.f;
        if (w0 + w < W_IN)
            v = x[(size_t)(c0 + cl) * NPIX + (size_t)h * W_IN + w0 + w];
        tile[cl][w] = v;
    }
    __syncthreads();

    int wc = t >> 2;           // 0..63
    int cc = (t & 3) * 16;     // 0,16,32,48
    if (w0 + wc < W_IN) {
        uint32_t pk[8];
        #pragma unroll
        for (int j = 0; j < 8; ++j) {
            unsigned short lo = f2bf(tile[cc + 2 * j][wc]);
            unsigned short hi = f2bf(tile[cc + 2 * j + 1][wc]);
            pk[j] = (uint32_t)lo | ((uint32_t)hi << 16);
        }
        size_t base = ((size_t)(h + 1) * WP + (w0 + wc + 1)) * C_IN + c0 + cc;
        uint4* dst = (uint4*)(xp + base);
        dst[0] = make_uint4(pk[0], pk[1], pk[2], pk[3]);
        dst[1] = make_uint4(pk[4], pk[5], pk[6], pk[7]);
    }
}

// W [O][C][3][3] f32 -> wb [p][O][C] bf16
__global__ void prep_w(const float* __restrict__ wk, unsigned short* __restrict__ wb) {
    int idx = blockIdx.x * 256 + threadIdx.x;         // 9*256*256 total
    int c = idx & 255, o = (idx >> 8) & 255, p = idx >> 16;
    wb[((size_t)p * 256 + o) * 256 + c] = f2bf(wk[((size_t)o * 256 + c) * 9 + p]);
}

// ---------- main GEMM: out[o][n] = sum_p sum_c wb[p][o][c] * xp[...][c] ----------
// Depth-2 counted-vmcnt pipeline, 3 LDS buffers. Per step: issue STAGE(t+2),
// s_waitcnt vmcnt(8) (t+1,t+2 in flight), barrier, COMPUTE(t),
// s_waitcnt lgkmcnt(0) (own ds_reads done -> after barrier ALL waves' reads
// done -> overwrite of buf t at step t+1 is race-free), barrier.
// sched_barrier(0) fences pin memory ops & MFMA inside their phase (rule #18).

__launch_bounds__(256, 3)
__global__ void conv_gemm(const unsigned short* __restrict__ xp,
                          const unsigned short* __restrict__ wb,
                          float* __restrict__ out) {
    // bijective XCD swizzle: 784 % 8 == 0, chunk = 98 per XCD
    int wgid = (blockIdx.x & 7) * 98 + (blockIdx.x >> 3);
    int mt = wgid & 1;
    int nt = wgid >> 1;
    int m0 = mt * BM;
    int n0 = nt * BN;
    int t  = threadIdx.x;
    int l  = t & 63, wv = t >> 6;

    // 3 bufs x (A 4096 + B 4096) elems = 48 KB
    __shared__ __align__(16) unsigned short lds[3 * 8192];

    // ---- staging: per matrix 8 chunks of 16 rows; wave wv owns chunks 2wv,2wv+1.
    // lane l -> row_in_chunk = l>>2, phys quad = l&3,
    // logical quad = (l&3) ^ (row&3) ^ ((row>>2)&3)
    int lq = (l & 3) ^ ((l >> 2) & 3) ^ ((l >> 4) & 3);
    int row0 = (wv * 2) * 16 + (l >> 2);
    int row1 = row0 + 16;
    int offA0 = (m0 + row0) * C_IN + lq * 8;
    int offA1 = (m0 + row1) * C_IN + lq * 8;
    int nc0 = n0 + row0, nc1 = n0 + row1;
    int h0 = nc0 / W_IN, w0c = nc0 - h0 * W_IN;
    int h1 = nc1 / W_IN, w1c = nc1 - h1 * W_IN;
    int offB0 = (h0 * WP + w0c) * C_IN + lq * 8;
    int offB1 = (h1 * WP + w1c) * C_IN + lq * 8;

    // ---- read-side fragment addressing ----
    int la = l & 15;
    int lk = l >> 4;                    // logical k-quad 0..3
    int mo = (wv >> 1) * 64;
    int no = (wv & 1) * 64;
    int pq = lk ^ (la & 3) ^ (la >> 2); // phys quad for ds_read (conflict-free)

    f32x4 acc[4][4];
    #pragma unroll
    for (int i = 0; i < 4; ++i)
        #pragma unroll
        for (int j = 0; j < 4; ++j)
            acc[i][j] = f32x4{0.f, 0.f, 0.f, 0.f};

#define STAGE(BD, S) do {                                                    \
    int s2_ = (S);                                                           \
    int p2_ = s2_ >> 3, cs2_ = (s2_ & 7) << 5;                               \
    int kh2_ = (p2_ * 11) >> 5; int kw2_ = p2_ - 3 * kh2_;                   \
    const unsigned short* aS_ = wb + p2_ * 65536 + cs2_;                     \
    const unsigned short* bS_ = xp + (kh2_ * WP + kw2_) * C_IN + cs2_;       \
    gl_lds16(aS_ + offA0, &lds[(BD) * 8192 + (wv * 2) * 512]);               \
    gl_lds16(aS_ + offA1, &lds[(BD) * 8192 + (wv * 2 + 1) * 512]);           \
    gl_lds16(bS_ + offB0, &lds[(BD) * 8192 + 4096 + (wv * 2) * 512]);        \
    gl_lds16(bS_ + offB1, &lds[(BD) * 8192 + 4096 + (wv * 2 + 1) * 512]);    \
} while (0)

#define COMPUTE(BC) do {                                                     \
    short8 af_[4], bf_[4];                                                   \
    _Pragma("unroll")                                                        \
    for (int i_ = 0; i_ < 4; ++i_)                                           \
        af_[i_] = *(const short8*)&lds[(BC) * 8192 + (mo + i_ * 16 + la) * BK + pq * 8]; \
    _Pragma("unroll")                                                        \
    for (int i_ = 0; i_ < 4; ++i_)                                           \
        bf_[i_] = *(const short8*)&lds[(BC) * 8192 + 4096 + (no + i_ * 16 + la) * BK + pq * 8]; \
    __builtin_amdgcn_s_setprio(1);                                           \
    _Pragma("unroll")                                                        \
    for (int i_ = 0; i_ < 4; ++i_)                                           \
        _Pragma("unroll")                                                    \
        for (int j_ = 0; j_ < 4; ++j_)                                       \
            acc[i_][j_] = __builtin_amdgcn_mfma_f32_16x16x32_bf16(           \
                af_[i_], bf_[j_], acc[i_][j_], 0, 0, 0);                     \
    __builtin_amdgcn_s_setprio(0);                                           \
} while (0)

#define GUARD_IN(VMSTR) do {                                                 \
    asm volatile("s_waitcnt " VMSTR ::: "memory");                           \
    __builtin_amdgcn_sched_barrier(0);                                       \
    __builtin_amdgcn_s_barrier();                                            \
    __builtin_amdgcn_sched_barrier(0);                                       \
} while (0)

#define GUARD_OUT() do {                                                     \
    asm volatile("s_waitcnt lgkmcnt(0)" ::: "memory");                       \
    __builtin_amdgcn_sched_barrier(0);                                       \
    __builtin_amdgcn_s_barrier();                                            \
    __builtin_amdgcn_sched_barrier(0);                                       \
} while (0)

#define BODY_S(BC, S) do {                                                   \
    STAGE(((BC) + 2) % 3, (S) + 2);                                          \
    GUARD_IN("vmcnt(8)");                                                    \
    COMPUTE(BC);                                                             \
    GUARD_OUT();                                                             \
} while (0)

    // 72 K-steps total (9 taps x 8 c-slices of 32)
    STAGE(0, 0);
    STAGE(1, 1);
    #pragma unroll 1
    for (int k = 0; k < 23; ++k) {      // computes s = 0..68
        int s = k * 3;
        BODY_S(0, s);
        BODY_S(1, s + 1);
        BODY_S(2, s + 2);
    }
    BODY_S(0, 69);                      // computes 69, stages s=71 into buf2
    GUARD_IN("vmcnt(4)");               // s=70 ready
    COMPUTE(1);
    GUARD_OUT();
    GUARD_IN("vmcnt(0)");               // s=71 ready
    COMPUTE(2);                         // final: no trailing guard needed

#undef BODY_S
#undef GUARD_OUT
#undef GUARD_IN
#undef COMPUTE
#undef STAGE

    // epilogue: D frag col = l&15 (n), row = (l>>4)*4 + r (o)
    int ro = lk * 4;
    #pragma unroll
    for (int i = 0; i < 4; ++i) {
        #pragma unroll
        for (int j = 0; j < 4; ++j) {
            int oo = m0 + mo + i * 16 + ro;
            int nn = n0 + no + j * 16 + la;
            #pragma unroll
            for (int r = 0; r < 4; ++r)
                out[(size_t)(oo + r) * NPIX + nn] = acc[i][j][r];
        }
    }
}

// ---------- fallback (tiny ws): naive direct conv, correct but slow ----------
__global__ void conv_naive(const float* __restrict__ x, const float* __restrict__ wk,
                           float* __restrict__ out) {
    int idx = blockIdx.x * 256 + threadIdx.x;   // o*NPIX + n
    int n = idx % NPIX;
    int o = idx / NPIX;
    int h = n / W_IN, w = n - (n / W_IN) * W_IN;
    float s = 0.f;
    for (int c = 0; c < C_IN; ++c) {
        const float* xc = x + (size_t)c * NPIX;
        const float* wc = wk + ((size_t)o * C_IN + c) * 9;
        #pragma unroll
        for (int kh = 0; kh < 3; ++kh) {
            int hh = h + kh - 1;
            if (hh < 0 || hh >= H_IN) continue;
            #pragma unroll
            for (int kw = 0; kw < 3; ++kw) {
                int ww = w + kw - 1;
                if (ww < 0 || ww >= W_IN) continue;
                s += xc[hh * W_IN + ww] * wc[kh * 3 + kw];
            }
        }
    }
    out[idx] = s;
}

extern "C" void kernel_launch(void* const* d_in, const int* in_sizes, int n_in,
                              void* d_out, int out_size, void* d_ws, size_t ws_size,
                              hipStream_t stream) {
    const float* x  = (const float*)d_in[0];
    const float* wk = (const float*)d_in[1];
    float* out = (float*)d_out;

    const size_t xp_elems = (size_t)HP * WP * C_IN;   // 13,075,456
    const size_t wb_elems = (size_t)9 * 256 * 256;    // 589,824
    const size_t need = (xp_elems + wb_elems) * 2;    // ~27.3 MB

    if (ws_size < need) {
        conv_naive<<<(C_OUT * NPIX) / 256, 256, 0, stream>>>(x, wk, out);
        return;
    }

    unsigned short* xp = (unsigned short*)d_ws;
    unsigned short* wb = xp + xp_elems;

    zero_border<<<113, 256, 0, stream>>>(xp);
    prep_x<<<224 * 16, 256, 0, stream>>>(x, xp);
    prep_w<<<2304, 256, 0, stream>>>(wk, wb);
    conv_gemm<<<392 * 2, 256, 0, stream>>>(xp, wb, out);
}

// Round 5
// 88.468 us; speedup vs baseline: 1.7164x; 1.2265x over previous
//
#include <hip/hip_runtime.h>
#include <hip/hip_bf16.h>
#include <stdint.h>

#define C_IN  256
#define C_OUT 256
#define H_IN  224
#define W_IN  224
#define HP    226
#define WP    226
#define NPIX  (H_IN * W_IN)   // 50176 = 392 * 128
#define BM    128
#define BN    128
#define BK    64              // 64 elems = 128 B rows -> XOR-(row&7) swizzle, 0 conflicts (r2 empirics)

typedef __attribute__((ext_vector_type(8))) short short8;
typedef __attribute__((ext_vector_type(4))) float f32x4;

__device__ __forceinline__ unsigned short f2bf(float f) {
    __hip_bfloat16 b = __float2bfloat16(f);
    return *(unsigned short*)&b;
}

// async global->LDS, 16B per lane; LDS dest is wave-uniform base + lane*16
__device__ __forceinline__ void gl_lds16(const unsigned short* g, unsigned short* l) {
    __builtin_amdgcn_global_load_lds(
        (const __attribute__((address_space(1))) unsigned int*)g,
        (__attribute__((address_space(3))) unsigned int*)l,
        16, 0, 0);
}

// ---------- prep kernels ----------

// zero only the pad border of xp [HP][WP][C] (interior written by prep_x)
__global__ void zero_border(unsigned short* __restrict__ xp) {
    int i = blockIdx.x * 256 + threadIdx.x;   // uint4 index
    uint4 z = make_uint4(0u, 0u, 0u, 0u);
    if (i < 7232) {                                    // h = 0 row
        ((uint4*)xp)[i] = z;
    } else if (i < 14464) {                            // h = 225 row
        ((uint4*)(xp + (size_t)225 * WP * C_IN))[i - 7232] = z;
    } else if (i < 21632) {                            // w = 0 col, h 1..224
        int j = i - 14464; int h = 1 + (j >> 5); int c4 = j & 31;
        ((uint4*)(xp + ((size_t)h * WP) * C_IN))[c4] = z;
    } else if (i < 28800) {                            // w = 225 col, h 1..224
        int j = i - 21632; int h = 1 + (j >> 5); int c4 = j & 31;
        ((uint4*)(xp + ((size_t)h * WP + 225) * C_IN))[c4] = z;
    }
}

// x [C][H][W] f32 -> xp [HP][WP][C] bf16 (interior only)
__global__ void prep_x(const float* __restrict__ x, unsigned short* __restrict__ xp) {
    int b  = blockIdx.x;
    int ct = b & 3, wt = (b >> 2) & 3, h = b >> 4;   // grid = 224*4*4
    int c0 = ct * 64, w0 = wt * 64;
    int t  = threadIdx.x;
    __shared__ float tile[64][65];

    int w   = t & 63;
    int cl0 = t >> 6;      // 0..3
    #pragma unroll
    for (int i = 0; i < 16; ++i) {
        int cl = i * 4 + cl0;
        float v = 0.f;
        if (w0 + w < W_IN)
            v = x[(size_t)(c0 + cl) * NPIX + (size_t)h * W_IN + w0 + w];
        tile[cl][w] = v;
    }
    __syncthreads();

    int wc = t >> 2;           // 0..63
    int cc = (t & 3) * 16;     // 0,16,32,48
    if (w0 + wc < W_IN) {
        uint32_t pk[8];
        #pragma unroll
        for (int j = 0; j < 8; ++j) {
            unsigned short lo = f2bf(tile[cc + 2 * j][wc]);
            unsigned short hi = f2bf(tile[cc + 2 * j + 1][wc]);
            pk[j] = (uint32_t)lo | ((uint32_t)hi << 16);
        }
        size_t base = ((size_t)(h + 1) * WP + (w0 + wc + 1)) * C_IN + c0 + cc;
        uint4* dst = (uint4*)(xp + base);
        dst[0] = make_uint4(pk[0], pk[1], pk[2], pk[3]);
        dst[1] = make_uint4(pk[4], pk[5], pk[6], pk[7]);
    }
}

// W [O][C][3][3] f32 -> wb [p][O][C] bf16
__global__ void prep_w(const float* __restrict__ wk, unsigned short* __restrict__ wb) {
    int idx = blockIdx.x * 256 + threadIdx.x;         // 9*256*256 total
    int c = idx & 255, o = (idx >> 8) & 255, p = idx >> 16;
    wb[((size_t)p * 256 + o) * 256 + c] = f2bf(wk[((size_t)o * 256 + c) * 9 + p]);
}

// ---------- main GEMM: out[o][n] = sum_p sum_c wb[p][o][c] * xp[...][c] ----------
// Minimum-2-phase counted-vmcnt pipeline (catalog T3/T4 recipe):
//   STAGE(buf^1, t+1) -> vmcnt(8) (t+1's 8 loads stay in flight across barrier)
//   -> barrier -> COMPUTE(buf) (16 ds_read_b128 + 32 MFMA) -> lgkmcnt(0) -> barrier.
// LDS: 2 bufs x (A 128x64 + B 128x64) bf16 = 64 KB. Swizzle (round-2 verified,
// 0 conflicts): phys_quad = logical_quad ^ (row & 7), write side via
// pre-swizzled global source, read side via XOR'd ds_read offset (rule #21).

__launch_bounds__(256, 2)
__global__ void conv_gemm(const unsigned short* __restrict__ xp,
                          const unsigned short* __restrict__ wb,
                          float* __restrict__ out) {
    // bijective XCD swizzle: 784 % 8 == 0, chunk = 98 per XCD
    int wgid = (blockIdx.x & 7) * 98 + (blockIdx.x >> 3);
    int mt = wgid & 1;
    int nt = wgid >> 1;
    int m0 = mt * BM;
    int n0 = nt * BN;
    int t  = threadIdx.x;
    int l  = t & 63, wv = t >> 6;

    __shared__ __align__(16) unsigned short lds[2 * 16384];   // 64 KB

    // ---- staging: per matrix 16 chunks of 8 rows (1 KB each); wave wv owns
    // chunks 4wv..4wv+3 of A and of B. lane l -> row_in_chunk = l>>3,
    // phys quad = l&7, logical quad q = (l&7) ^ (row&7) = (l&7) ^ (l>>3).
    int q8 = ((l & 7) ^ (l >> 3)) * 8;
    int rA = l >> 3;
    int offA0, offA1, offA2, offA3, offB0, offB1, offB2, offB3;
    {
        int r0 = (wv * 4 + 0) * 8 + rA;
        int r1 = (wv * 4 + 1) * 8 + rA;
        int r2 = (wv * 4 + 2) * 8 + rA;
        int r3 = (wv * 4 + 3) * 8 + rA;
        offA0 = (m0 + r0) * C_IN + q8;
        offA1 = (m0 + r1) * C_IN + q8;
        offA2 = (m0 + r2) * C_IN + q8;
        offA3 = (m0 + r3) * C_IN + q8;
        int nc0 = n0 + r0, nc1 = n0 + r1, nc2 = n0 + r2, nc3 = n0 + r3;
        int h0 = nc0 / W_IN, h1 = nc1 / W_IN, h2 = nc2 / W_IN, h3 = nc3 / W_IN;
        offB0 = (h0 * WP + (nc0 - h0 * W_IN)) * C_IN + q8;
        offB1 = (h1 * WP + (nc1 - h1 * W_IN)) * C_IN + q8;
        offB2 = (h2 * WP + (nc2 - h2 * W_IN)) * C_IN + q8;
        offB3 = (h3 * WP + (nc3 - h3 * W_IN)) * C_IN + q8;
    }

    // ---- read-side fragment addressing ----
    int la = l & 15;
    int lk = l >> 4;                    // k sub-quad 0..3
    int mo = (wv >> 1) * 64;
    int no = (wv & 1) * 64;
    // k-slice ks: logical quad = ks*4 + lk; phys = logical ^ (row&7), row&7 = la&7
    int xq0 = ((0 * 4 + lk) ^ (la & 7)) * 8;
    int xq1 = ((1 * 4 + lk) ^ (la & 7)) * 8;

    f32x4 acc[4][4];
    #pragma unroll
    for (int i = 0; i < 4; ++i)
        #pragma unroll
        for (int j = 0; j < 4; ++j)
            acc[i][j] = f32x4{0.f, 0.f, 0.f, 0.f};

#define STAGE(BD, S) do {                                                    \
    int s_ = (S);                                                            \
    int p_ = s_ >> 2, cs_ = (s_ & 3) << 6;                                   \
    int kh_ = (p_ * 11) >> 5; int kw_ = p_ - 3 * kh_;                        \
    const unsigned short* aS_ = wb + p_ * 65536 + cs_;                       \
    const unsigned short* bS_ = xp + (kh_ * WP + kw_) * C_IN + cs_;          \
    gl_lds16(aS_ + offA0, &lds[(BD) * 16384 + (wv * 4 + 0) * 512]);          \
    gl_lds16(aS_ + offA1, &lds[(BD) * 16384 + (wv * 4 + 1) * 512]);          \
    gl_lds16(aS_ + offA2, &lds[(BD) * 16384 + (wv * 4 + 2) * 512]);          \
    gl_lds16(aS_ + offA3, &lds[(BD) * 16384 + (wv * 4 + 3) * 512]);          \
    gl_lds16(bS_ + offB0, &lds[(BD) * 16384 + 8192 + (wv * 4 + 0) * 512]);   \
    gl_lds16(bS_ + offB1, &lds[(BD) * 16384 + 8192 + (wv * 4 + 1) * 512]);   \
    gl_lds16(bS_ + offB2, &lds[(BD) * 16384 + 8192 + (wv * 4 + 2) * 512]);   \
    gl_lds16(bS_ + offB3, &lds[(BD) * 16384 + 8192 + (wv * 4 + 3) * 512]);   \
} while (0)

#define COMPUTE(BC) do {                                                     \
    short8 af_[4][2], bf_[4][2];                                             \
    _Pragma("unroll")                                                        \
    for (int i_ = 0; i_ < 4; ++i_) {                                         \
        af_[i_][0] = *(const short8*)&lds[(BC) * 16384 + (mo + i_ * 16 + la) * BK + xq0]; \
        af_[i_][1] = *(const short8*)&lds[(BC) * 16384 + (mo + i_ * 16 + la) * BK + xq1]; \
    }                                                                        \
    _Pragma("unroll")                                                        \
    for (int i_ = 0; i_ < 4; ++i_) {                                         \
        bf_[i_][0] = *(const short8*)&lds[(BC) * 16384 + 8192 + (no + i_ * 16 + la) * BK + xq0]; \
        bf_[i_][1] = *(const short8*)&lds[(BC) * 16384 + 8192 + (no + i_ * 16 + la) * BK + xq1]; \
    }                                                                        \
    __builtin_amdgcn_s_setprio(1);                                           \
    _Pragma("unroll")                                                        \
    for (int i_ = 0; i_ < 4; ++i_)                                           \
        _Pragma("unroll")                                                    \
        for (int j_ = 0; j_ < 4; ++j_)                                       \
            acc[i_][j_] = __builtin_amdgcn_mfma_f32_16x16x32_bf16(           \
                af_[i_][0], bf_[j_][0], acc[i_][j_], 0, 0, 0);               \
    _Pragma("unroll")                                                        \
    for (int i_ = 0; i_ < 4; ++i_)                                           \
        _Pragma("unroll")                                                    \
        for (int j_ = 0; j_ < 4; ++j_)                                       \
            acc[i_][j_] = __builtin_amdgcn_mfma_f32_16x16x32_bf16(           \
                af_[i_][1], bf_[j_][1], acc[i_][j_], 0, 0, 0);               \
    __builtin_amdgcn_s_setprio(0);                                           \
} while (0)

#define GUARD_IN(VMSTR) do {                                                 \
    asm volatile("s_waitcnt " VMSTR ::: "memory");                           \
    __builtin_amdgcn_sched_barrier(0);                                       \
    __builtin_amdgcn_s_barrier();                                            \
    __builtin_amdgcn_sched_barrier(0);                                       \
} while (0)

#define GUARD_OUT() do {                                                     \
    asm volatile("s_waitcnt lgkmcnt(0)" ::: "memory");                       \
    __builtin_amdgcn_sched_barrier(0);                                       \
    __builtin_amdgcn_s_barrier();                                            \
    __builtin_amdgcn_sched_barrier(0);                                       \
} while (0)

#define BODY(BC, S) do {                                                     \
    STAGE((BC) ^ 1, (S) + 1);                                                \
    GUARD_IN("vmcnt(8)");                                                    \
    COMPUTE(BC);                                                             \
    GUARD_OUT();                                                             \
} while (0)

    // 36 K-steps total (9 taps x 4 c-slices of 64)
    STAGE(0, 0);
    #pragma unroll 1
    for (int k = 0; k < 17; ++k) {      // computes s = 0..33
        BODY(0, 2 * k);
        BODY(1, 2 * k + 1);
    }
    BODY(0, 34);                        // computes 34, stages 35 into buf1
    GUARD_IN("vmcnt(0)");               // s=35 ready
    COMPUTE(1);                         // final step, no trailing guard

#undef BODY
#undef GUARD_OUT
#undef GUARD_IN
#undef COMPUTE
#undef STAGE

    // epilogue: D frag col = l&15 (n), row = (l>>4)*4 + r (o)
    int ro = lk * 4;
    #pragma unroll
    for (int i = 0; i < 4; ++i) {
        #pragma unroll
        for (int j = 0; j < 4; ++j) {
            int oo = m0 + mo + i * 16 + ro;
            int nn = n0 + no + j * 16 + la;
            #pragma unroll
            for (int r = 0; r < 4; ++r)
                out[(size_t)(oo + r) * NPIX + nn] = acc[i][j][r];
        }
    }
}

// ---------- fallback (tiny ws): naive direct conv, correct but slow ----------
__global__ void conv_naive(const float* __restrict__ x, const float* __restrict__ wk,
                           float* __restrict__ out) {
    int idx = blockIdx.x * 256 + threadIdx.x;   // o*NPIX + n
    int n = idx % NPIX;
    int o = idx / NPIX;
    int h = n / W_IN, w = n - (n / W_IN) * W_IN;
    float s = 0.f;
    for (int c = 0; c < C_IN; ++c) {
        const float* xc = x + (size_t)c * NPIX;
        const float* wc = wk + ((size_t)o * C_IN + c) * 9;
        #pragma unroll
        for (int kh = 0; kh < 3; ++kh) {
            int hh = h + kh - 1;
            if (hh < 0 || hh >= H_IN) continue;
            #pragma unroll
            for (int kw = 0; kw < 3; ++kw) {
                int ww = w + kw - 1;
                if (ww < 0 || ww >= W_IN) continue;
                s += xc[hh * W_IN + ww] * wc[kh * 3 + kw];
            }
        }
    }
    out[idx] = s;
}

extern "C" void kernel_launch(void* const* d_in, const int* in_sizes, int n_in,
                              void* d_out, int out_size, void* d_ws, size_t ws_size,
                              hipStream_t stream) {
    const float* x  = (const float*)d_in[0];
    const float* wk = (const float*)d_in[1];
    float* out = (float*)d_out;

    const size_t xp_elems = (size_t)HP * WP * C_IN;   // 13,075,456
    const size_t wb_elems = (size_t)9 * 256 * 256;    // 589,824
    const size_t need = (xp_elems + wb_elems) * 2;    // ~27.3 MB

    if (ws_size < need) {
        conv_naive<<<(C_OUT * NPIX) / 256, 256, 0, stream>>>(x, wk, out);
        return;
    }

    unsigned short* xp = (unsigned short*)d_ws;
    unsigned short* wb = xp + xp_elems;

    zero_border<<<113, 256, 0, stream>>>(xp);
    prep_x<<<224 * 16, 256, 0, stream>>>(x, xp);
    prep_w<<<2304, 256, 0, stream>>>(wk, wb);
    conv_gemm<<<392 * 2, 256, 0, stream>>>(xp, wb, out);
}